// Round 1
// baseline (558.245 us; speedup 1.0000x reference)
//
#include <hip/hip_runtime.h>
#include <hip/hip_bf16.h>

#define NFEAT 128
#define HID 16
#define NACT 18
#define NGRAPH 64

__global__ __launch_bounds__(256) void k_init_deg(float* deg, int N) {
    int i = blockIdx.x * 256 + threadIdx.x;
    if (i < N) deg[i] = 1.0f;   // self-loop weight
}

__global__ __launch_bounds__(256) void k_deg_add(float* deg, const int* __restrict__ dst,
                                                 const float* __restrict__ w, int E) {
    int e = blockIdx.x * 256 + threadIdx.x;
    if (e < E) unsafeAtomicAdd(&deg[dst[e]], w[e]);
}

__global__ __launch_bounds__(256) void k_dinv(float* deg, int N) {
    int i = blockIdx.x * 256 + threadIdx.x;
    if (i < N) {
        float d = deg[i];
        deg[i] = d > 0.f ? rsqrtf(d) : 0.f;
    }
}

// h[n][j] = sum_k x[n][k] * W1[k][j]; 16 nodes per block
__global__ __launch_bounds__(256) void k_gemm1(const float* __restrict__ x,
                                               const float* __restrict__ W1,
                                               float* __restrict__ h) {
    __shared__ float xs[16 * 132];       // padded stride: bank = (4r+k)%32, conflict-free
    __shared__ float ws[NFEAT * HID];
    int t = threadIdx.x;
    for (int i = t; i < NFEAT * HID; i += 256) ws[i] = W1[i];
    const float* xblk = x + (size_t)blockIdx.x * 16 * NFEAT;
    #pragma unroll
    for (int rep = 0; rep < 2; rep++) {
        int i4 = (rep * 256 + t) * 4;
        int row = i4 >> 7, col = i4 & 127;
        float4 v = *reinterpret_cast<const float4*>(xblk + i4);
        *reinterpret_cast<float4*>(&xs[row * 132 + col]) = v;
    }
    __syncthreads();
    int r = t >> 4, j = t & 15;
    float acc = 0.f;
    #pragma unroll
    for (int k = 0; k < NFEAT; k++) acc += xs[r * 132 + k] * ws[k * HID + j];
    h[((size_t)blockIdx.x * 16 + r) * HID + j] = acc;
}

// agg[dst][j] += dinv[src]*w*dinv[dst] * h[src][j]  (real edges only; self-loop in consumer)
__global__ __launch_bounds__(256) void k_aggregate(float* __restrict__ agg,
                                                   const float* __restrict__ h,
                                                   const int* __restrict__ src,
                                                   const int* __restrict__ dst,
                                                   const float* __restrict__ w,
                                                   const float* __restrict__ dinv, int E) {
    int gid = blockIdx.x * 256 + threadIdx.x;
    int e = gid >> 4, j = gid & 15;
    if (e < E) {
        int s = src[e], d = dst[e];
        float nrm = dinv[s] * w[e] * dinv[d];
        unsafeAtomicAdd(&agg[(size_t)d * HID + j], nrm * h[(size_t)s * HID + j]);
    }
}

// h2[n][j] = sum_k relu(agg[n][k] + dinv[n]^2*h[n][k] + b1[k]) * W2[k][j]
__global__ __launch_bounds__(256) void k_gemm2(const float* __restrict__ agg,
                                               const float* __restrict__ h,
                                               const float* __restrict__ dinv,
                                               const float* __restrict__ b1,
                                               const float* __restrict__ W2,
                                               float* __restrict__ h2, int N) {
    __shared__ float ws[HID * HID];
    __shared__ float bs[HID];
    int t = threadIdx.x;
    if (t < HID * HID) ws[t] = W2[t];
    if (t < HID) bs[t] = b1[t];
    __syncthreads();
    int gid = blockIdx.x * 256 + t;
    int n = gid >> 4, j = gid & 15;
    if (n < N) {
        float sn = dinv[n]; sn *= sn;
        float acc = 0.f;
        #pragma unroll
        for (int k = 0; k < HID; k++) {
            float a = agg[n * HID + k] + sn * h[n * HID + k] + bs[k];
            a = a > 0.f ? a : 0.f;
            acc += a * ws[k * HID + j];
        }
        h2[n * HID + j] = acc;
    }
}

// pooled[g][j] = max over nodes of relu(agg[n][j] + dinv^2*h2[n][j] + b2[j])
// values >= 0 so uint bit-pattern max == float max; init 0 matches empty-segment guard
__global__ __launch_bounds__(256) void k_pool(const float* __restrict__ agg,
                                              const float* __restrict__ h2,
                                              const float* __restrict__ dinv,
                                              const float* __restrict__ b2,
                                              const int* __restrict__ batch,
                                              unsigned* __restrict__ pooled, int N) {
    __shared__ unsigned pl[NGRAPH * HID];
    __shared__ float bs[HID];
    int t = threadIdx.x;
    for (int i = t; i < NGRAPH * HID; i += 256) pl[i] = 0u;
    if (t < HID) bs[t] = b2[t];
    __syncthreads();
    int n = blockIdx.x * 256 + t;
    if (n < N) {
        int g = batch[n];
        float sn = dinv[n]; sn *= sn;
        #pragma unroll
        for (int j = 0; j < HID; j++) {
            float v = agg[n * HID + j] + sn * h2[n * HID + j] + bs[j];
            v = v > 0.f ? v : 0.f;
            atomicMax(&pl[g * HID + j], __float_as_uint(v));
        }
    }
    __syncthreads();
    for (int i = t; i < NGRAPH * HID; i += 256) {
        unsigned b = pl[i];
        if (b) atomicMax(&pooled[i], b);
    }
}

__global__ __launch_bounds__(256) void k_final(const unsigned* __restrict__ pooled,
                                               const float* __restrict__ Wl,
                                               const float* __restrict__ bl,
                                               float* __restrict__ out) {
    int gid = blockIdx.x * 256 + threadIdx.x;
    if (gid < NGRAPH * NACT) {
        int g = gid / NACT, a = gid - g * NACT;
        float acc = bl[a];
        #pragma unroll
        for (int k = 0; k < HID; k++)
            acc += __uint_as_float(pooled[g * HID + k]) * Wl[k * NACT + a];
        out[gid] = acc;
    }
}

extern "C" void kernel_launch(void* const* d_in, const int* in_sizes, int n_in,
                              void* d_out, int out_size, void* d_ws, size_t ws_size,
                              hipStream_t stream) {
    const float* x     = (const float*)d_in[0];
    const int*   ei    = (const int*)d_in[1];
    const float* ew    = (const float*)d_in[2];
    const int*   batch = (const int*)d_in[3];
    const float* W1    = (const float*)d_in[4];
    const float* b1    = (const float*)d_in[5];
    const float* W2    = (const float*)d_in[6];
    const float* b2    = (const float*)d_in[7];
    const float* Wl    = (const float*)d_in[8];
    const float* bl    = (const float*)d_in[9];
    float* out = (float*)d_out;

    int N = in_sizes[0] / NFEAT;
    int E = in_sizes[1] / 2;
    const int* srcIdx = ei;
    const int* dstIdx = ei + E;

    float* ws    = (float*)d_ws;
    float* dinv  = ws;                        // [N]
    float* h     = dinv + N;                  // [N*HID]
    float* h2    = h + (size_t)N * HID;       // [N*HID]
    float* agg   = h2 + (size_t)N * HID;      // [N*HID]
    unsigned* pooled = (unsigned*)(agg + (size_t)N * HID);  // [NGRAPH*HID]

    int nbN = (N + 255) / 256;
    int nbE = (E + 255) / 256;
    int nbEH = (int)(((long long)E * HID + 255) / 256);
    int nbNH = (int)(((long long)N * HID + 255) / 256);

    hipMemsetAsync(agg, 0, (size_t)N * HID * sizeof(float), stream);
    hipMemsetAsync(pooled, 0, NGRAPH * HID * sizeof(unsigned), stream);

    k_init_deg<<<nbN, 256, 0, stream>>>(dinv, N);
    k_deg_add<<<nbE, 256, 0, stream>>>(dinv, dstIdx, ew, E);
    k_dinv<<<nbN, 256, 0, stream>>>(dinv, N);

    k_gemm1<<<N / 16, 256, 0, stream>>>(x, W1, h);
    k_aggregate<<<nbEH, 256, 0, stream>>>(agg, h, srcIdx, dstIdx, ew, dinv, E);
    k_gemm2<<<nbNH, 256, 0, stream>>>(agg, h, dinv, b1, W2, h2, N);

    hipMemsetAsync(agg, 0, (size_t)N * HID * sizeof(float), stream);
    k_aggregate<<<nbEH, 256, 0, stream>>>(agg, h2, srcIdx, dstIdx, ew, dinv, E);

    k_pool<<<nbN, 256, 0, stream>>>(agg, h2, dinv, b2, batch, pooled, N);
    k_final<<<(NGRAPH * NACT + 255) / 256, 256, 0, stream>>>(pooled, Wl, bl, out);
}